// Round 9
// baseline (294.603 us; speedup 1.0000x reference)
//
#include <hip/hip_runtime.h>

#define B_ 2
#define T_ 4096
#define C_ 768
#define H_ 12
#define D_ 64
#define WQTASK 384     /* wave-tasks per XCD queue: 3 bh * 128 q-slices */

typedef __attribute__((ext_vector_type(8))) short bf16x8;
typedef __attribute__((ext_vector_type(4))) float f32x4;
typedef __attribute__((ext_vector_type(16))) float f32x16;

__device__ __forceinline__ unsigned short f2bf(float f) {
  union { float f; unsigned u; } v; v.f = f;
  unsigned r = v.u + 0x7fffu + ((v.u >> 16) & 1u);
  return (unsigned short)(r >> 16);
}

__device__ __forceinline__ float exp2_hw(float x) {
  float r;
  asm("v_exp_f32 %0, %1" : "=v"(r) : "v"(x));
  return r;
}

__device__ __forceinline__ void gll16(const void* g, void* l) {
  __builtin_amdgcn_global_load_lds((const __attribute__((address_space(1))) void*)g,
                                   (__attribute__((address_space(3))) void*)l, 16, 0, 0);
}

// ---------------- cast kernels ----------------

// f32 -> bf16 (coalesced); resets the 8 task-queue counters
__global__ __launch_bounds__(256) void cast_bf16_k(const float* __restrict__ in,
                                                   unsigned short* __restrict__ out, int n4,
                                                   unsigned* __restrict__ cnt) {
  int i = blockIdx.x * 256 + threadIdx.x;
  if (i < 128) cnt[i] = 0u;
  if (i >= n4) return;
  float4 v = ((const float4*)in)[i];
  union { unsigned short s[4]; unsigned long long u; } o;
  o.s[0] = f2bf(v.x); o.s[1] = f2bf(v.y); o.s[2] = f2bf(v.z); o.s[3] = f2bf(v.w);
  ((unsigned long long*)out)[i] = o.u;
}

// in [R][C] f32 -> out [C][R] bf16, 64x64 tiles via LDS (coalesced both sides)
__global__ __launch_bounds__(256) void tpose_cast_k(const float* __restrict__ in,
                                                    unsigned short* __restrict__ out,
                                                    int R, int C) {
  __shared__ unsigned short t[64][65];
  const int c0 = blockIdx.x * 64, r0 = blockIdx.y * 64;
  const int tr = threadIdx.x >> 6, tc = threadIdx.x & 63;
#pragma unroll
  for (int i = 0; i < 16; ++i) {
    int r = i * 4 + tr;
    t[r][tc] = f2bf(in[(size_t)(r0 + r) * C + c0 + tc]);
  }
  __syncthreads();
#pragma unroll
  for (int i = 0; i < 16; ++i) {
    int c = i * 4 + tr;
    out[(size_t)(c0 + c) * R + r0 + tc] = t[tc][c];
  }
}

// ---------------- GEMM (R5 structure, unchanged) ----------------

#define QSCALE 0.1803368801111243f /* 0.125 * log2(e) */

template <int MODE>
__global__ __launch_bounds__(256) void gemm_k(const unsigned short* __restrict__ A,
                                              const unsigned short* __restrict__ Bt,
                                              int K,
                                              unsigned short* __restrict__ q_out,
                                              unsigned short* __restrict__ k_out,
                                              unsigned short* __restrict__ vt_out,
                                              float* __restrict__ f_out,
                                              const float* __restrict__ bias) {
  __shared__ short a_lds[2][128 * 32];
  __shared__ short b_lds[2][128 * 32];
  const int tid = threadIdx.x;
  const int wave = tid >> 6, lane = tid & 63;
  const int wm = wave >> 1, wn = wave & 1;
  const int lr = lane & 15, lc = lane >> 4;

  const int id = blockIdx.x;
  const int xcd = id & 7, idc = id >> 3;
  const int bx = xcd * 8 + (idc & 7);
  const int by = idc >> 3;
  const int m0 = bx * 128, n0 = by * 128;

  f32x4 acc[4][4];
  for (int mi = 0; mi < 4; ++mi)
    for (int ni = 0; ni < 4; ++ni) acc[mi][ni] = (f32x4){0.f, 0.f, 0.f, 0.f};

  const unsigned short *ap[2], *bp[2];
  int lb[2];
#pragma unroll
  for (int p = 0; p < 2; ++p) {
    int chunk = p * 256 + wave * 64 + lane;
    int r = chunk >> 2, cc = chunk & 3;
    int c = cc ^ ((r >> 1) & 3);
    ap[p] = A + (size_t)(m0 + r) * K + c * 8;
    bp[p] = Bt + (size_t)(n0 + r) * K + c * 8;
    lb[p] = (p * 256 + wave * 64) * 8;
  }

  const int nks = K >> 5;
#pragma unroll
  for (int p = 0; p < 2; ++p) {
    gll16(ap[p], &a_lds[0][lb[p]]);
    gll16(bp[p], &b_lds[0][lb[p]]);
    ap[p] += 32; bp[p] += 32;
  }

  for (int ks = 0; ks < nks; ++ks) {
    const int buf = ks & 1;
    __builtin_amdgcn_s_barrier();
    __builtin_amdgcn_sched_barrier(0);
    if (ks + 1 < nks) {
#pragma unroll
      for (int p = 0; p < 2; ++p) {
        gll16(ap[p], &a_lds[buf ^ 1][lb[p]]);
        gll16(bp[p], &b_lds[buf ^ 1][lb[p]]);
        ap[p] += 32; bp[p] += 32;
      }
      asm volatile("s_waitcnt vmcnt(4)" ::: "memory");
    } else {
      asm volatile("s_waitcnt vmcnt(0)" ::: "memory");
    }
    __builtin_amdgcn_sched_barrier(0);
    __builtin_amdgcn_s_barrier();
    __builtin_amdgcn_sched_barrier(0);

    bf16x8 af[4], bfrag[4];
#pragma unroll
    for (int mi = 0; mi < 4; ++mi) {
      int r = wm * 64 + mi * 16 + lr;
      af[mi] = *(const bf16x8*)&a_lds[buf][r * 32 + (lc ^ ((r >> 1) & 3)) * 8];
    }
#pragma unroll
    for (int ni = 0; ni < 4; ++ni) {
      int r = wn * 64 + ni * 16 + lr;
      bfrag[ni] = *(const bf16x8*)&b_lds[buf][r * 32 + (lc ^ ((r >> 1) & 3)) * 8];
    }
    __builtin_amdgcn_s_setprio(1);
#pragma unroll
    for (int mi = 0; mi < 4; ++mi)
#pragma unroll
      for (int ni = 0; ni < 4; ++ni)
        acc[mi][ni] = __builtin_amdgcn_mfma_f32_16x16x32_bf16(af[mi], bfrag[ni], acc[mi][ni], 0, 0, 0);
    __builtin_amdgcn_s_setprio(0);
  }

  if (MODE == 0) {
    const int nn0 = n0 + wn * 64 + lr;
    const int which = n0 / 768;
#pragma unroll
    for (int mi = 0; mi < 4; ++mi)
#pragma unroll
      for (int ni = 0; ni < 4; ++ni) {
        int nn = nn0 + ni * 16;
        int rem = nn - which * 768;
        int h = rem >> 6, d = rem & 63;
        int t0v = m0 + wm * 64 + mi * 16 + lc * 4;
        int b = t0v >> 12, t = t0v & (T_ - 1);
        size_t bh = (size_t)(b * H_ + h);
        if (which == 2) {
          unsigned u0, u1;
          asm("v_cvt_pk_bf16_f32 %0, %1, %2" : "=v"(u0) : "v"(acc[mi][ni][0]), "v"(acc[mi][ni][1]));
          asm("v_cvt_pk_bf16_f32 %0, %1, %2" : "=v"(u1) : "v"(acc[mi][ni][2]), "v"(acc[mi][ni][3]));
          uint2 u = {u0, u1};
          *(uint2*)&vt_out[(bh * D_ + d) * T_ + t] = u;
        } else {
#pragma unroll
          for (int r = 0; r < 4; ++r) {
            float av = acc[mi][ni][r];
            if (which == 0) av *= QSCALE;
            unsigned short val = f2bf(av);
            if (which == 0) q_out[(bh * T_ + t + r) * D_ + d] = val;
            else            k_out[(bh * T_ + t + r) * D_ + d] = val;
          }
        }
      }
  } else {
#pragma unroll
    for (int mi = 0; mi < 4; ++mi)
#pragma unroll
      for (int ni = 0; ni < 4; ++ni) {
        int nn = n0 + wn * 64 + ni * 16 + lr;
        float bv = bias[nn];
#pragma unroll
        for (int r = 0; r < 4; ++r) {
          int m = m0 + wm * 64 + mi * 16 + lc * 4 + r;
          f_out[(size_t)m * C_ + nn] = acc[mi][ni][r] + bv;
        }
      }
  }
}

// ---------------- flash attention v9: wave-autonomous, ZERO barriers ----------------
// Each WAVE pops its own task (bh, 32-row q-slice) from its XCD queue (LPT heavy
// first); no __syncthreads / s_barrier anywhere. Wave-private 16KB LDS region:
// stage K/V frags with gll16 (wave-coalesced), ds_read_b128 to VGPRs, re-stage
// next tile into the same buffer (reads retired before writes issue), compute.
// Counted vmcnt(8): stage(j+1) stays in flight under compute(j). Waves desync
// freely -> pipes stay fed; setprio(1) arbitration now has role diversity.

#define PACK8(SV, O)                                                              \
  do {                                                                            \
    unsigned w0, w1, w2, w3, w4, w5, w6, w7;                                      \
    asm("v_cvt_pk_bf16_f32 %0, %1, %2" : "=v"(w0) : "v"(SV[0]), "v"(SV[1]));      \
    asm("v_cvt_pk_bf16_f32 %0, %1, %2" : "=v"(w1) : "v"(SV[2]), "v"(SV[3]));      \
    asm("v_cvt_pk_bf16_f32 %0, %1, %2" : "=v"(w2) : "v"(SV[4]), "v"(SV[5]));      \
    asm("v_cvt_pk_bf16_f32 %0, %1, %2" : "=v"(w3) : "v"(SV[6]), "v"(SV[7]));      \
    asm("v_cvt_pk_bf16_f32 %0, %1, %2" : "=v"(w4) : "v"(SV[8]), "v"(SV[9]));      \
    asm("v_cvt_pk_bf16_f32 %0, %1, %2" : "=v"(w5) : "v"(SV[10]), "v"(SV[11]));    \
    asm("v_cvt_pk_bf16_f32 %0, %1, %2" : "=v"(w6) : "v"(SV[12]), "v"(SV[13]));    \
    asm("v_cvt_pk_bf16_f32 %0, %1, %2" : "=v"(w7) : "v"(SV[14]), "v"(SV[15]));    \
    asm("v_permlane32_swap_b32 %0, %1" : "+v"(w0), "+v"(w2));                     \
    asm("v_permlane32_swap_b32 %0, %1" : "+v"(w1), "+v"(w3));                     \
    asm("v_permlane32_swap_b32 %0, %1" : "+v"(w4), "+v"(w6));                     \
    asm("v_permlane32_swap_b32 %0, %1" : "+v"(w5), "+v"(w7));                     \
    pw[(O) + 0] = w0; pw[(O) + 1] = w1; pw[(O) + 2] = w2; pw[(O) + 3] = w3;       \
    pw[(O) + 4] = w4; pw[(O) + 5] = w5; pw[(O) + 6] = w6; pw[(O) + 7] = w7;       \
  } while (0)

__global__ __launch_bounds__(256) void flash9_k(const unsigned short* __restrict__ Qg,
                                                const unsigned short* __restrict__ Kg,
                                                const unsigned short* __restrict__ Vtg,
                                                unsigned short* __restrict__ Og,
                                                unsigned* __restrict__ cnt) {
  __shared__ short lds[4][2][8 * 512];   // [wave][K|V][frag*512] : 64 KB

  const int tid = threadIdx.x;
  const int wave = tid >> 6, lane = tid & 63;
  const int lq = lane & 31, hi = lane >> 5;
  short* kbuf = &lds[wave][0][0];
  short* vbuf = &lds[wave][1][0];
  const int xq = blockIdx.x & 7;
  unsigned* myq = cnt + xq * 16;

  for (;;) {
    int t = 0;
    if (lane == 0) t = (int)atomicAdd(myq, 1u);
    t = __shfl(t, 0);
    if (t >= WQTASK) return;

    const int d3 = t / 3;
    const int qs = 127 - d3;            // LPT: heavy q-slices first
    const int bh = xq * 3 + (t - d3 * 3);
    const int qw = qs * 32;
    const int q_g = qw + lq;
    const int ntw = (qs >> 1) + 1;      // 64-key tiles this wave computes

    const size_t kbase = (size_t)bh * T_ * D_;
    const size_t vbase = (size_t)bh * D_ * T_;

    // Q B-frags (pre-scaled by 0.125*log2e in GEMM1)
    const unsigned short* qrow = Qg + kbase + (size_t)q_g * D_;
    bf16x8 qf[4];
#pragma unroll
    for (int tt = 0; tt < 4; ++tt) qf[tt] = *(const bf16x8*)(qrow + tt * 16 + hi * 8);

    f32x16 accT0, accT1;
#pragma unroll
    for (int r = 0; r < 16; ++r) { accT0[r] = 0.f; accT1[r] = 0.f; }
    float lvec[8];
#pragma unroll
    for (int r = 0; r < 8; ++r) lvec[r] = 0.f;
    float m = 0.f;

    // stage tile it: 8 K frags then 8 V frags (issue order matters for vmcnt)
    auto stageK = [&](int it) {
#pragma unroll
      for (int tt = 0; tt < 4; ++tt)
#pragma unroll
        for (int h = 0; h < 2; ++h)
          gll16(Kg + kbase + (size_t)(it * 64 + h * 32 + lq) * D_ + tt * 16 + hi * 8,
                kbuf + (tt * 2 + h) * 512);
    };
    auto stageV = [&](int it) {
#pragma unroll
      for (int tt = 0; tt < 4; ++tt)
#pragma unroll
        for (int h = 0; h < 2; ++h)
          gll16(Vtg + vbase + (size_t)(h * 32 + lq) * T_ + it * 64 + tt * 16 + hi * 8,
                vbuf + (tt * 2 + h) * 512);
    };

    stageK(0);
    stageV(0);

    for (int j = 0; j < ntw; ++j) {
      const int kv = j * 64;
      const bool pf = (j + 1 < ntw);

      // ---- phase 1: K(j) -> regs, restage K(j+1), QK^T ----
      asm volatile("s_waitcnt vmcnt(8)" ::: "memory");   // K(j) landed
      __builtin_amdgcn_sched_barrier(0);
      bf16x8 kf[8];
#pragma unroll
      for (int f = 0; f < 8; ++f) kf[f] = *(const bf16x8*)&kbuf[f * 512 + lane * 8];
      asm volatile("s_waitcnt lgkmcnt(0)" ::: "memory");
      __builtin_amdgcn_sched_barrier(0);
      if (pf) stageK(j + 1);

      const float negm = -m;
      f32x16 s0, s1;
#pragma unroll
      for (int r = 0; r < 16; ++r) { s0[r] = negm; s1[r] = negm; }
      __builtin_amdgcn_s_setprio(1);
#pragma unroll
      for (int tt = 0; tt < 4; ++tt) {
        s0 = __builtin_amdgcn_mfma_f32_32x32x16_bf16(kf[2 * tt], qf[tt], s0, 0, 0, 0);
        s1 = __builtin_amdgcn_mfma_f32_32x32x16_bf16(kf[2 * tt + 1], qf[tt], s1, 0, 0, 0);
      }
      __builtin_amdgcn_s_setprio(0);

      // ---- phase 2: V(j) -> regs, restage V(j+1) ----
      if (pf) { asm volatile("s_waitcnt vmcnt(8)" ::: "memory"); }
      else    { asm volatile("s_waitcnt vmcnt(0)" ::: "memory"); }
      __builtin_amdgcn_sched_barrier(0);
      bf16x8 vf[8];
#pragma unroll
      for (int f = 0; f < 8; ++f) vf[f] = *(const bf16x8*)&vbuf[f * 512 + lane * 8];
      asm volatile("s_waitcnt lgkmcnt(0)" ::: "memory");
      __builtin_amdgcn_sched_barrier(0);
      if (pf) stageV(j + 1);

      // ---- causal mask (last tile only) ----
      if (kv + 63 > qw) {
#pragma unroll
        for (int r = 0; r < 16; ++r) {
          int key0 = kv + ((r & 3) + 8 * (r >> 2) + 4 * hi);
          if (key0 > q_g) s0[r] = -INFINITY;
          if (key0 + 32 > q_g) s1[r] = -INFINITY;
        }
      }

      // ---- online softmax (relative-max, defer-rescale) ----
      float mx[16];
#pragma unroll
      for (int r = 0; r < 16; ++r) mx[r] = fmaxf(s0[r], s1[r]);
      float a0 = fmaxf(fmaxf(mx[0], mx[1]), mx[2]);
      float a1 = fmaxf(fmaxf(mx[3], mx[4]), mx[5]);
      float a2 = fmaxf(fmaxf(mx[6], mx[7]), mx[8]);
      float a3 = fmaxf(fmaxf(mx[9], mx[10]), mx[11]);
      float a4 = fmaxf(fmaxf(mx[12], mx[13]), mx[14]);
      float rx = fmaxf(fmaxf(fmaxf(a0, a1), fmaxf(a2, a3)), fmaxf(a4, mx[15]));
      rx = fmaxf(rx, __shfl_xor(rx, 32));

      if (!__all(rx <= 8.f)) {
        float dlt = fmaxf(rx, 0.f);
        float al = exp2_hw(-dlt);
        m += dlt;
#pragma unroll
        for (int r = 0; r < 16; ++r) { accT0[r] *= al; accT1[r] *= al; }
#pragma unroll
        for (int r = 0; r < 8; ++r) lvec[r] *= al;
#pragma unroll
        for (int r = 0; r < 16; ++r) { s0[r] -= dlt; s1[r] -= dlt; }
      }
#pragma unroll
      for (int r = 0; r < 16; ++r) s0[r] = exp2_hw(s0[r]);
#pragma unroll
      for (int r = 0; r < 16; ++r) s1[r] = exp2_hw(s1[r]);
#pragma unroll
      for (int r = 0; r < 8; ++r) lvec[r] += (s0[r] + s1[r]) + (s0[r + 8] + s1[r + 8]);

      // ---- P^T -> bf16 B-frags ----
      unsigned pw[16];
      PACK8(s0, 0);
      PACK8(s1, 8);

      // ---- O^T += Vt P^T ----
      __builtin_amdgcn_s_setprio(1);
#pragma unroll
      for (int ks = 0; ks < 4; ++ks) {
        union { unsigned u[4]; bf16x8 v; } pb;
        pb.u[0] = pw[ks * 4 + 0]; pb.u[1] = pw[ks * 4 + 1];
        pb.u[2] = pw[ks * 4 + 2]; pb.u[3] = pw[ks * 4 + 3];
        accT0 = __builtin_amdgcn_mfma_f32_32x32x16_bf16(vf[2 * ks], pb.v, accT0, 0, 0, 0);
        accT1 = __builtin_amdgcn_mfma_f32_32x32x16_bf16(vf[2 * ks + 1], pb.v, accT1, 0, 0, 0);
      }
      __builtin_amdgcn_s_setprio(0);
    }

    // ---- final l reduce + epilogue ----
    float l = 0.f;
#pragma unroll
    for (int r = 0; r < 8; ++r) l += lvec[r];
    l += __shfl_xor(l, 32);
    const float inv = 1.0f / l;
    const int b = bh / H_, h = bh - b * H_;
    unsigned short* orow = Og + ((size_t)b * T_ + q_g) * C_ + h * D_;
#pragma unroll
    for (int g = 0; g < 4; ++g) {
      int d0 = 8 * g + 4 * hi;
      float e0 = accT0[4 * g + 0] * inv, e1 = accT0[4 * g + 1] * inv;
      float e2 = accT0[4 * g + 2] * inv, e3 = accT0[4 * g + 3] * inv;
      float f0 = accT1[4 * g + 0] * inv, f1 = accT1[4 * g + 1] * inv;
      float f2 = accT1[4 * g + 2] * inv, f3 = accT1[4 * g + 3] * inv;
      uint2 ua, ub;
      asm("v_cvt_pk_bf16_f32 %0, %1, %2" : "=v"(ua.x) : "v"(e0), "v"(e1));
      asm("v_cvt_pk_bf16_f32 %0, %1, %2" : "=v"(ua.y) : "v"(e2), "v"(e3));
      asm("v_cvt_pk_bf16_f32 %0, %1, %2" : "=v"(ub.x) : "v"(f0), "v"(f1));
      asm("v_cvt_pk_bf16_f32 %0, %1, %2" : "=v"(ub.y) : "v"(f2), "v"(f3));
      *(uint2*)(orow + d0) = ua;
      *(uint2*)(orow + 32 + d0) = ub;
    }
    // no sync needed: LDS region is wave-private
  }
}

// ---------------- launcher ----------------

extern "C" void kernel_launch(void* const* d_in, const int* in_sizes, int n_in,
                              void* d_out, int out_size, void* d_ws, size_t ws_size,
                              hipStream_t stream) {
  const float* x     = (const float*)d_in[0];
  const float* Wqkv  = (const float*)d_in[1];
  const float* Wproj = (const float*)d_in[2];
  const float* bproj = (const float*)d_in[3];
  float* out = (float*)d_out;

  char* ws = (char*)d_ws;
  unsigned short* xbf   = (unsigned short*)(ws);
  unsigned short* wqkvt = (unsigned short*)(ws + 12582912);
  unsigned short* wprjt = (unsigned short*)(ws + 16121856);
  unsigned short* Qb    = (unsigned short*)(ws + 17301504);
  unsigned short* Kb    = (unsigned short*)(ws + 29884416);
  unsigned short* Vtb   = (unsigned short*)(ws + 42467328);
  unsigned*       cnt   = (unsigned*)(ws + 55050240);  // 128 u32

  cast_bf16_k<<<6144, 256, 0, stream>>>(x, xbf, (B_ * T_ * C_) / 4, cnt);
  tpose_cast_k<<<dim3((3 * C_) / 64, C_ / 64), 256, 0, stream>>>(Wqkv, wqkvt, C_, 3 * C_);
  tpose_cast_k<<<dim3(C_ / 64, C_ / 64), 256, 0, stream>>>(Wproj, wprjt, C_, C_);

  gemm_k<0><<<(B_ * T_ / 128) * (3 * C_ / 128), 256, 0, stream>>>(
      xbf, wqkvt, C_, Qb, Kb, Vtb, nullptr, nullptr);

  flash9_k<<<512, 256, 0, stream>>>(Qb, Kb, Vtb, xbf, cnt);

  gemm_k<1><<<(B_ * T_ / 128) * (C_ / 128), 256, 0, stream>>>(
      xbf, wprjt, C_, nullptr, nullptr, nullptr, out, bproj);
}

// Round 10
// 248.870 us; speedup vs baseline: 1.1838x; 1.1838x over previous
//
#include <hip/hip_runtime.h>

#define B_ 2
#define T_ 4096
#define C_ 768
#define H_ 12
#define D_ 64
#define QTASK 96       /* tasks per XCD queue: 3 bh * 32 qi */

typedef __attribute__((ext_vector_type(8))) short bf16x8;
typedef __attribute__((ext_vector_type(4))) float f32x4;
typedef __attribute__((ext_vector_type(16))) float f32x16;

__device__ __forceinline__ unsigned short f2bf(float f) {
  union { float f; unsigned u; } v; v.f = f;
  unsigned r = v.u + 0x7fffu + ((v.u >> 16) & 1u);
  return (unsigned short)(r >> 16);
}

__device__ __forceinline__ float exp2_hw(float x) {
  float r;
  asm("v_exp_f32 %0, %1" : "=v"(r) : "v"(x));
  return r;
}

__device__ __forceinline__ void gll16(const void* g, void* l) {
  __builtin_amdgcn_global_load_lds((const __attribute__((address_space(1))) void*)g,
                                   (__attribute__((address_space(3))) void*)l, 16, 0, 0);
}

// ---------------- cast kernels ----------------

// f32 -> bf16 (coalesced); resets the 8 task-queue counters
__global__ __launch_bounds__(256) void cast_bf16_k(const float* __restrict__ in,
                                                   unsigned short* __restrict__ out, int n4,
                                                   unsigned* __restrict__ cnt) {
  int i = blockIdx.x * 256 + threadIdx.x;
  if (i < 128) cnt[i] = 0u;
  if (i >= n4) return;
  float4 v = ((const float4*)in)[i];
  union { unsigned short s[4]; unsigned long long u; } o;
  o.s[0] = f2bf(v.x); o.s[1] = f2bf(v.y); o.s[2] = f2bf(v.z); o.s[3] = f2bf(v.w);
  ((unsigned long long*)out)[i] = o.u;
}

// in [R][C] f32 -> out [C][R] bf16, 64x64 tiles via LDS (coalesced both sides)
__global__ __launch_bounds__(256) void tpose_cast_k(const float* __restrict__ in,
                                                    unsigned short* __restrict__ out,
                                                    int R, int C) {
  __shared__ unsigned short t[64][65];
  const int c0 = blockIdx.x * 64, r0 = blockIdx.y * 64;
  const int tr = threadIdx.x >> 6, tc = threadIdx.x & 63;
#pragma unroll
  for (int i = 0; i < 16; ++i) {
    int r = i * 4 + tr;
    t[r][tc] = f2bf(in[(size_t)(r0 + r) * C + c0 + tc]);
  }
  __syncthreads();
#pragma unroll
  for (int i = 0; i < 16; ++i) {
    int c = i * 4 + tr;
    out[(size_t)(c0 + c) * R + r0 + tc] = t[tc][c];
  }
}

// ---------------- GEMM (R5 structure, unchanged) ----------------

#define QSCALE 0.1803368801111243f /* 0.125 * log2(e) */

template <int MODE>
__global__ __launch_bounds__(256) void gemm_k(const unsigned short* __restrict__ A,
                                              const unsigned short* __restrict__ Bt,
                                              int K,
                                              unsigned short* __restrict__ q_out,
                                              unsigned short* __restrict__ k_out,
                                              unsigned short* __restrict__ vt_out,
                                              float* __restrict__ f_out,
                                              const float* __restrict__ bias) {
  __shared__ short a_lds[2][128 * 32];
  __shared__ short b_lds[2][128 * 32];
  const int tid = threadIdx.x;
  const int wave = tid >> 6, lane = tid & 63;
  const int wm = wave >> 1, wn = wave & 1;
  const int lr = lane & 15, lc = lane >> 4;

  const int id = blockIdx.x;
  const int xcd = id & 7, idc = id >> 3;
  const int bx = xcd * 8 + (idc & 7);
  const int by = idc >> 3;
  const int m0 = bx * 128, n0 = by * 128;

  f32x4 acc[4][4];
  for (int mi = 0; mi < 4; ++mi)
    for (int ni = 0; ni < 4; ++ni) acc[mi][ni] = (f32x4){0.f, 0.f, 0.f, 0.f};

  const unsigned short *ap[2], *bp[2];
  int lb[2];
#pragma unroll
  for (int p = 0; p < 2; ++p) {
    int chunk = p * 256 + wave * 64 + lane;
    int r = chunk >> 2, cc = chunk & 3;
    int c = cc ^ ((r >> 1) & 3);
    ap[p] = A + (size_t)(m0 + r) * K + c * 8;
    bp[p] = Bt + (size_t)(n0 + r) * K + c * 8;
    lb[p] = (p * 256 + wave * 64) * 8;
  }

  const int nks = K >> 5;
#pragma unroll
  for (int p = 0; p < 2; ++p) {
    gll16(ap[p], &a_lds[0][lb[p]]);
    gll16(bp[p], &b_lds[0][lb[p]]);
    ap[p] += 32; bp[p] += 32;
  }

  for (int ks = 0; ks < nks; ++ks) {
    const int buf = ks & 1;
    __builtin_amdgcn_s_barrier();
    __builtin_amdgcn_sched_barrier(0);
    if (ks + 1 < nks) {
#pragma unroll
      for (int p = 0; p < 2; ++p) {
        gll16(ap[p], &a_lds[buf ^ 1][lb[p]]);
        gll16(bp[p], &b_lds[buf ^ 1][lb[p]]);
        ap[p] += 32; bp[p] += 32;
      }
      asm volatile("s_waitcnt vmcnt(4)" ::: "memory");
    } else {
      asm volatile("s_waitcnt vmcnt(0)" ::: "memory");
    }
    __builtin_amdgcn_sched_barrier(0);
    __builtin_amdgcn_s_barrier();
    __builtin_amdgcn_sched_barrier(0);

    bf16x8 af[4], bfrag[4];
#pragma unroll
    for (int mi = 0; mi < 4; ++mi) {
      int r = wm * 64 + mi * 16 + lr;
      af[mi] = *(const bf16x8*)&a_lds[buf][r * 32 + (lc ^ ((r >> 1) & 3)) * 8];
    }
#pragma unroll
    for (int ni = 0; ni < 4; ++ni) {
      int r = wn * 64 + ni * 16 + lr;
      bfrag[ni] = *(const bf16x8*)&b_lds[buf][r * 32 + (lc ^ ((r >> 1) & 3)) * 8];
    }
    __builtin_amdgcn_s_setprio(1);
#pragma unroll
    for (int mi = 0; mi < 4; ++mi)
#pragma unroll
      for (int ni = 0; ni < 4; ++ni)
        acc[mi][ni] = __builtin_amdgcn_mfma_f32_16x16x32_bf16(af[mi], bfrag[ni], acc[mi][ni], 0, 0, 0);
    __builtin_amdgcn_s_setprio(0);
  }

  if (MODE == 0) {
    const int nn0 = n0 + wn * 64 + lr;
    const int which = n0 / 768;
#pragma unroll
    for (int mi = 0; mi < 4; ++mi)
#pragma unroll
      for (int ni = 0; ni < 4; ++ni) {
        int nn = nn0 + ni * 16;
        int rem = nn - which * 768;
        int h = rem >> 6, d = rem & 63;
        int t0v = m0 + wm * 64 + mi * 16 + lc * 4;
        int b = t0v >> 12, t = t0v & (T_ - 1);
        size_t bh = (size_t)(b * H_ + h);
        if (which == 2) {
          unsigned u0, u1;
          asm("v_cvt_pk_bf16_f32 %0, %1, %2" : "=v"(u0) : "v"(acc[mi][ni][0]), "v"(acc[mi][ni][1]));
          asm("v_cvt_pk_bf16_f32 %0, %1, %2" : "=v"(u1) : "v"(acc[mi][ni][2]), "v"(acc[mi][ni][3]));
          uint2 u = {u0, u1};
          *(uint2*)&vt_out[(bh * D_ + d) * T_ + t] = u;
        } else {
#pragma unroll
          for (int r = 0; r < 4; ++r) {
            float av = acc[mi][ni][r];
            if (which == 0) av *= QSCALE;
            unsigned short val = f2bf(av);
            if (which == 0) q_out[(bh * T_ + t + r) * D_ + d] = val;
            else            k_out[(bh * T_ + t + r) * D_ + d] = val;
          }
        }
      }
  } else {
#pragma unroll
    for (int mi = 0; mi < 4; ++mi)
#pragma unroll
      for (int ni = 0; ni < 4; ++ni) {
        int nn = n0 + wn * 64 + ni * 16 + lr;
        float bv = bias[nn];
#pragma unroll
        for (int r = 0; r < 4; ++r) {
          int m = m0 + wm * 64 + mi * 16 + lc * 4 + r;
          f_out[(size_t)m * C_ + nn] = acc[mi][ni][r] + bv;
        }
      }
  }
}

// ---------------- flash attention v10: KVBLK=128 (2 sub-tiles per pipeline iter) ----------------
// Per-XCD dynamic queues (64 workers vs 96 tasks, LPT). 512 blocks, 4 waves.
// Iteration = 128 keys: stage 32KB (8 gll16/wave), QK for 2 subs, ONE combined
// softmax pass over 64 scores/lane, 16 PV MFMAs. Two-barrier counted-vmcnt(8)
// double buffer (proven R5 scheme). Frag-linear LDS (conflict-free).

#define PACK8(SV, PW, O)                                                          \
  do {                                                                            \
    unsigned w0, w1, w2, w3, w4, w5, w6, w7;                                      \
    asm("v_cvt_pk_bf16_f32 %0, %1, %2" : "=v"(w0) : "v"(SV[0]), "v"(SV[1]));      \
    asm("v_cvt_pk_bf16_f32 %0, %1, %2" : "=v"(w1) : "v"(SV[2]), "v"(SV[3]));      \
    asm("v_cvt_pk_bf16_f32 %0, %1, %2" : "=v"(w2) : "v"(SV[4]), "v"(SV[5]));      \
    asm("v_cvt_pk_bf16_f32 %0, %1, %2" : "=v"(w3) : "v"(SV[6]), "v"(SV[7]));      \
    asm("v_cvt_pk_bf16_f32 %0, %1, %2" : "=v"(w4) : "v"(SV[8]), "v"(SV[9]));      \
    asm("v_cvt_pk_bf16_f32 %0, %1, %2" : "=v"(w5) : "v"(SV[10]), "v"(SV[11]));    \
    asm("v_cvt_pk_bf16_f32 %0, %1, %2" : "=v"(w6) : "v"(SV[12]), "v"(SV[13]));    \
    asm("v_cvt_pk_bf16_f32 %0, %1, %2" : "=v"(w7) : "v"(SV[14]), "v"(SV[15]));    \
    asm("v_permlane32_swap_b32 %0, %1" : "+v"(w0), "+v"(w2));                     \
    asm("v_permlane32_swap_b32 %0, %1" : "+v"(w1), "+v"(w3));                     \
    asm("v_permlane32_swap_b32 %0, %1" : "+v"(w4), "+v"(w6));                     \
    asm("v_permlane32_swap_b32 %0, %1" : "+v"(w5), "+v"(w7));                     \
    PW[(O) + 0] = w0; PW[(O) + 1] = w1; PW[(O) + 2] = w2; PW[(O) + 3] = w3;       \
    PW[(O) + 4] = w4; PW[(O) + 5] = w5; PW[(O) + 6] = w6; PW[(O) + 7] = w7;       \
  } while (0)

__global__ __launch_bounds__(256) void flash10_k(const unsigned short* __restrict__ Qg,
                                                 const unsigned short* __restrict__ Kg,
                                                 const unsigned short* __restrict__ Vtg,
                                                 unsigned short* __restrict__ Og,
                                                 unsigned* __restrict__ cnt) {
  __shared__ short k_lds[2][16 * 512];   // 32 KB
  __shared__ short vt_lds[2][16 * 512];  // 32 KB
  __shared__ int task_s;

  const int tid = threadIdx.x;
  const int wave = tid >> 6, lane = tid & 63;
  const int lq = lane & 31, hi = lane >> 5;
  const int xq = blockIdx.x & 7;
  unsigned* myq = cnt + xq * 16;

  for (;;) {
    if (tid == 0) task_s = (int)atomicAdd(myq, 1u);
    __syncthreads();
    const int task = task_s;
    if (task >= QTASK) return;

    const int qi = 31 - task / 3;       // LPT: heavy first
    const int bh = xq * 3 + (task - (task / 3) * 3);
    const int qw = qi * 128 + wave * 32;
    const int q_g = qw + lq;

    const size_t kbase = (size_t)bh * T_ * D_;
    const size_t vbase = (size_t)bh * D_ * T_;

    const unsigned short* qrow = Qg + kbase + (size_t)q_g * D_;
    bf16x8 qf[4];
#pragma unroll
    for (int t = 0; t < 4; ++t) qf[t] = *(const bf16x8*)(qrow + t * 16 + hi * 8);

    f32x16 accT0, accT1;
#pragma unroll
    for (int r = 0; r < 16; ++r) { accT0[r] = 0.f; accT1[r] = 0.f; }
    float lvec[8];
#pragma unroll
    for (int r = 0; r < 8; ++r) lvec[r] = 0.f;
    float m = 0.f;

    const int nt = qi + 1;              // 128-key iterations

    // hoisted per-p staging bases: frag f = wave + p*4 (covers 0..15)
    const unsigned short *kb_p[4], *vb_p[4];
    int lf[4];
#pragma unroll
    for (int p = 0; p < 4; ++p) {
      int f = wave + p * 4;
      int sub = f >> 3, tt = (f >> 1) & 3, h = f & 1;
      kb_p[p] = Kg + kbase + (size_t)(sub * 64 + h * 32 + lq) * D_ + tt * 16 + hi * 8;
      vb_p[p] = Vtg + vbase + (size_t)(h * 32 + lq) * T_ + sub * 64 + tt * 16 + hi * 8;
      lf[p] = f * 512;
    }

    auto stage = [&](int it, int sb) {
#pragma unroll
      for (int p = 0; p < 4; ++p) {
        gll16(kb_p[p] + (size_t)it * 128 * D_, &k_lds[sb][lf[p]]);
        gll16(vb_p[p] + it * 128, &vt_lds[sb][lf[p]]);
      }
    };

    stage(0, 0);

    for (int j = 0; j < nt; ++j) {
      const int kv = j * 128;
      const int buf = j & 1;

      __builtin_amdgcn_s_barrier();     // all waves done compute(j-1)
      __builtin_amdgcn_sched_barrier(0);
      if (j + 1 < nt) {
        stage(j + 1, buf ^ 1);
        asm volatile("s_waitcnt vmcnt(8)" ::: "memory");  // stage(j) landed
      } else {
        asm volatile("s_waitcnt vmcnt(0)" ::: "memory");
      }
      __builtin_amdgcn_sched_barrier(0);
      __builtin_amdgcn_s_barrier();     // buf[j&1] ready for everyone
      __builtin_amdgcn_sched_barrier(0);

      const bool act1 = (kv + 64 <= qw + 31);  // sub-tile 1 not fully masked
      const float negm = -m;

      // ---- QK^T sub0 (keys kv..kv+63) ----
      f32x16 s0, s1;
#pragma unroll
      for (int r = 0; r < 16; ++r) { s0[r] = negm; s1[r] = negm; }
      __builtin_amdgcn_s_setprio(1);
#pragma unroll
      for (int t = 0; t < 4; ++t) {
        bf16x8 kf0 = *(const bf16x8*)&k_lds[buf][(t * 2 + 0) * 512 + lane * 8];
        bf16x8 kf1 = *(const bf16x8*)&k_lds[buf][(t * 2 + 1) * 512 + lane * 8];
        s0 = __builtin_amdgcn_mfma_f32_32x32x16_bf16(kf0, qf[t], s0, 0, 0, 0);
        s1 = __builtin_amdgcn_mfma_f32_32x32x16_bf16(kf1, qf[t], s1, 0, 0, 0);
      }
      __builtin_amdgcn_s_setprio(0);

      // ---- QK^T sub1 (keys kv+64..kv+127) ----
      f32x16 s2, s3;
      if (act1) {
#pragma unroll
        for (int r = 0; r < 16; ++r) { s2[r] = negm; s3[r] = negm; }
        __builtin_amdgcn_s_setprio(1);
#pragma unroll
        for (int t = 0; t < 4; ++t) {
          bf16x8 kf0 = *(const bf16x8*)&k_lds[buf][(8 + t * 2 + 0) * 512 + lane * 8];
          bf16x8 kf1 = *(const bf16x8*)&k_lds[buf][(8 + t * 2 + 1) * 512 + lane * 8];
          s2 = __builtin_amdgcn_mfma_f32_32x32x16_bf16(kf0, qf[t], s2, 0, 0, 0);
          s3 = __builtin_amdgcn_mfma_f32_32x32x16_bf16(kf1, qf[t], s3, 0, 0, 0);
        }
        __builtin_amdgcn_s_setprio(0);
      }

      // ---- causal masks (diagonal region only) ----
      if (kv + 63 > qw) {
#pragma unroll
        for (int r = 0; r < 16; ++r) {
          int key0 = kv + ((r & 3) + 8 * (r >> 2) + 4 * hi);
          if (key0 > q_g) s0[r] = -INFINITY;
          if (key0 + 32 > q_g) s1[r] = -INFINITY;
        }
      }
      if (act1 && kv + 127 > qw) {
#pragma unroll
        for (int r = 0; r < 16; ++r) {
          int key0 = kv + 64 + ((r & 3) + 8 * (r >> 2) + 4 * hi);
          if (key0 > q_g) s2[r] = -INFINITY;
          if (key0 + 32 > q_g) s3[r] = -INFINITY;
        }
      }

      // ---- combined softmax over (up to) 64 scores/lane ----
      float mx[16];
#pragma unroll
      for (int r = 0; r < 16; ++r) mx[r] = fmaxf(s0[r], s1[r]);
      if (act1) {
#pragma unroll
        for (int r = 0; r < 16; ++r) mx[r] = fmaxf(mx[r], fmaxf(s2[r], s3[r]));
      }
      float a0 = fmaxf(fmaxf(mx[0], mx[1]), mx[2]);
      float a1 = fmaxf(fmaxf(mx[3], mx[4]), mx[5]);
      float a2 = fmaxf(fmaxf(mx[6], mx[7]), mx[8]);
      float a3 = fmaxf(fmaxf(mx[9], mx[10]), mx[11]);
      float a4 = fmaxf(fmaxf(mx[12], mx[13]), mx[14]);
      float rx = fmaxf(fmaxf(fmaxf(a0, a1), fmaxf(a2, a3)), fmaxf(a4, mx[15]));
      rx = fmaxf(rx, __shfl_xor(rx, 32));

      if (!__all(rx <= 8.f)) {
        float dlt = fmaxf(rx, 0.f);
        float al = exp2_hw(-dlt);
        m += dlt;
#pragma unroll
        for (int r = 0; r < 16; ++r) { accT0[r] *= al; accT1[r] *= al; }
#pragma unroll
        for (int r = 0; r < 8; ++r) lvec[r] *= al;
#pragma unroll
        for (int r = 0; r < 16; ++r) { s0[r] -= dlt; s1[r] -= dlt; }
        if (act1) {
#pragma unroll
          for (int r = 0; r < 16; ++r) { s2[r] -= dlt; s3[r] -= dlt; }
        }
      }

#pragma unroll
      for (int r = 0; r < 16; ++r) s0[r] = exp2_hw(s0[r]);
#pragma unroll
      for (int r = 0; r < 16; ++r) s1[r] = exp2_hw(s1[r]);
#pragma unroll
      for (int r = 0; r < 8; ++r) lvec[r] += (s0[r] + s1[r]) + (s0[r + 8] + s1[r + 8]);
      unsigned pw0[16], pw1[16];
      PACK8(s0, pw0, 0);
      PACK8(s1, pw0, 8);
      if (act1) {
#pragma unroll
        for (int r = 0; r < 16; ++r) s2[r] = exp2_hw(s2[r]);
#pragma unroll
        for (int r = 0; r < 16; ++r) s3[r] = exp2_hw(s3[r]);
#pragma unroll
        for (int r = 0; r < 8; ++r) lvec[r] += (s2[r] + s3[r]) + (s2[r + 8] + s3[r + 8]);
        PACK8(s2, pw1, 0);
        PACK8(s3, pw1, 8);
      }

      // ---- O^T += Vt P^T (sub0, then sub1) ----
      __builtin_amdgcn_s_setprio(1);
#pragma unroll
      for (int ks = 0; ks < 4; ++ks) {
        union { unsigned u[4]; bf16x8 v; } pb;
        pb.u[0] = pw0[ks * 4 + 0]; pb.u[1] = pw0[ks * 4 + 1];
        pb.u[2] = pw0[ks * 4 + 2]; pb.u[3] = pw0[ks * 4 + 3];
        bf16x8 vf0 = *(const bf16x8*)&vt_lds[buf][(ks * 2 + 0) * 512 + lane * 8];
        bf16x8 vf1 = *(const bf16x8*)&vt_lds[buf][(ks * 2 + 1) * 512 + lane * 8];
        accT0 = __builtin_amdgcn_mfma_f32_32x32x16_bf16(vf0, pb.v, accT0, 0, 0, 0);
        accT1 = __builtin_amdgcn_mfma_f32_32x32x16_bf16(vf1, pb.v, accT1, 0, 0, 0);
      }
      if (act1) {
#pragma unroll
        for (int ks = 0; ks < 4; ++ks) {
          union { unsigned u[4]; bf16x8 v; } pb;
          pb.u[0] = pw1[ks * 4 + 0]; pb.u[1] = pw1[ks * 4 + 1];
          pb.u[2] = pw1[ks * 4 + 2]; pb.u[3] = pw1[ks * 4 + 3];
          bf16x8 vf0 = *(const bf16x8*)&vt_lds[buf][(8 + ks * 2 + 0) * 512 + lane * 8];
          bf16x8 vf1 = *(const bf16x8*)&vt_lds[buf][(8 + ks * 2 + 1) * 512 + lane * 8];
          accT0 = __builtin_amdgcn_mfma_f32_32x32x16_bf16(vf0, pb.v, accT0, 0, 0, 0);
          accT1 = __builtin_amdgcn_mfma_f32_32x32x16_bf16(vf1, pb.v, accT1, 0, 0, 0);
        }
      }
      __builtin_amdgcn_s_setprio(0);
    }

    // ---- final l reduce + epilogue ----
    float l = 0.f;
#pragma unroll
    for (int r = 0; r < 8; ++r) l += lvec[r];
    l += __shfl_xor(l, 32);
    const float inv = 1.0f / l;
    const int b = bh / H_, h = bh - b * H_;
    unsigned short* orow = Og + ((size_t)b * T_ + q_g) * C_ + h * D_;
#pragma unroll
    for (int g = 0; g < 4; ++g) {
      int d0 = 8 * g + 4 * hi;
      float e0 = accT0[4 * g + 0] * inv, e1 = accT0[4 * g + 1] * inv;
      float e2 = accT0[4 * g + 2] * inv, e3 = accT0[4 * g + 3] * inv;
      float f0 = accT1[4 * g + 0] * inv, f1 = accT1[4 * g + 1] * inv;
      float f2 = accT1[4 * g + 2] * inv, f3 = accT1[4 * g + 3] * inv;
      uint2 ua, ub;
      asm("v_cvt_pk_bf16_f32 %0, %1, %2" : "=v"(ua.x) : "v"(e0), "v"(e1));
      asm("v_cvt_pk_bf16_f32 %0, %1, %2" : "=v"(ua.y) : "v"(e2), "v"(e3));
      asm("v_cvt_pk_bf16_f32 %0, %1, %2" : "=v"(ub.x) : "v"(f0), "v"(f1));
      asm("v_cvt_pk_bf16_f32 %0, %1, %2" : "=v"(ub.y) : "v"(f2), "v"(f3));
      *(uint2*)(orow + d0) = ua;
      *(uint2*)(orow + 32 + d0) = ub;
    }
    __syncthreads();  // quiesce LDS before next pop
  }
}

// ---------------- launcher ----------------

extern "C" void kernel_launch(void* const* d_in, const int* in_sizes, int n_in,
                              void* d_out, int out_size, void* d_ws, size_t ws_size,
                              hipStream_t stream) {
  const float* x     = (const float*)d_in[0];
  const float* Wqkv  = (const float*)d_in[1];
  const float* Wproj = (const float*)d_in[2];
  const float* bproj = (const float*)d_in[3];
  float* out = (float*)d_out;

  char* ws = (char*)d_ws;
  unsigned short* xbf   = (unsigned short*)(ws);
  unsigned short* wqkvt = (unsigned short*)(ws + 12582912);
  unsigned short* wprjt = (unsigned short*)(ws + 16121856);
  unsigned short* Qb    = (unsigned short*)(ws + 17301504);
  unsigned short* Kb    = (unsigned short*)(ws + 29884416);
  unsigned short* Vtb   = (unsigned short*)(ws + 42467328);
  unsigned*       cnt   = (unsigned*)(ws + 55050240);  // 128 u32

  cast_bf16_k<<<6144, 256, 0, stream>>>(x, xbf, (B_ * T_ * C_) / 4, cnt);
  tpose_cast_k<<<dim3((3 * C_) / 64, C_ / 64), 256, 0, stream>>>(Wqkv, wqkvt, C_, 3 * C_);
  tpose_cast_k<<<dim3(C_ / 64, C_ / 64), 256, 0, stream>>>(Wproj, wprjt, C_, C_);

  gemm_k<0><<<(B_ * T_ / 128) * (3 * C_ / 128), 256, 0, stream>>>(
      xbf, wqkvt, C_, Qb, Kb, Vtb, nullptr, nullptr);

  flash10_k<<<512, 256, 0, stream>>>(Qb, Kb, Vtb, xbf, cnt);

  gemm_k<1><<<(B_ * T_ / 128) * (C_ / 128), 256, 0, stream>>>(
      xbf, wprjt, C_, nullptr, nullptr, nullptr, out, bproj);
}

// Round 11
// 195.236 us; speedup vs baseline: 1.5090x; 1.2747x over previous
//
#include <hip/hip_runtime.h>

#define B_ 2
#define T_ 4096
#define C_ 768
#define H_ 12
#define D_ 64
#define QTASK 96       /* tasks per XCD queue: 3 bh * 32 qi */

typedef __attribute__((ext_vector_type(8))) short bf16x8;
typedef __attribute__((ext_vector_type(4))) float f32x4;
typedef __attribute__((ext_vector_type(16))) float f32x16;

__device__ __forceinline__ unsigned short f2bf(float f) {
  union { float f; unsigned u; } v; v.f = f;
  unsigned r = v.u + 0x7fffu + ((v.u >> 16) & 1u);
  return (unsigned short)(r >> 16);
}

__device__ __forceinline__ float exp2_hw(float x) {
  float r;
  asm("v_exp_f32 %0, %1" : "=v"(r) : "v"(x));
  return r;
}

__device__ __forceinline__ void gll16(const void* g, void* l) {
  __builtin_amdgcn_global_load_lds((const __attribute__((address_space(1))) void*)g,
                                   (__attribute__((address_space(3))) void*)l, 16, 0, 0);
}

// ---------------- cast kernels ----------------

// f32 -> bf16 (coalesced); resets the 8 task-queue counters
__global__ __launch_bounds__(256) void cast_bf16_k(const float* __restrict__ in,
                                                   unsigned short* __restrict__ out, int n4,
                                                   unsigned* __restrict__ cnt) {
  int i = blockIdx.x * 256 + threadIdx.x;
  if (i < 128) cnt[i] = 0u;
  if (i >= n4) return;
  float4 v = ((const float4*)in)[i];
  union { unsigned short s[4]; unsigned long long u; } o;
  o.s[0] = f2bf(v.x); o.s[1] = f2bf(v.y); o.s[2] = f2bf(v.z); o.s[3] = f2bf(v.w);
  ((unsigned long long*)out)[i] = o.u;
}

// in [R][C] f32 -> out [C][R] bf16, 64x64 tiles via LDS (coalesced both sides)
__global__ __launch_bounds__(256) void tpose_cast_k(const float* __restrict__ in,
                                                    unsigned short* __restrict__ out,
                                                    int R, int C) {
  __shared__ unsigned short t[64][65];
  const int c0 = blockIdx.x * 64, r0 = blockIdx.y * 64;
  const int tr = threadIdx.x >> 6, tc = threadIdx.x & 63;
#pragma unroll
  for (int i = 0; i < 16; ++i) {
    int r = i * 4 + tr;
    t[r][tc] = f2bf(in[(size_t)(r0 + r) * C + c0 + tc]);
  }
  __syncthreads();
#pragma unroll
  for (int i = 0; i < 16; ++i) {
    int c = i * 4 + tr;
    out[(size_t)(c0 + c) * R + r0 + tc] = t[tc][c];
  }
}

// ---------------- GEMM (R5 structure, unchanged) ----------------

#define QSCALE 0.1803368801111243f /* 0.125 * log2(e) */

template <int MODE>
__global__ __launch_bounds__(256) void gemm_k(const unsigned short* __restrict__ A,
                                              const unsigned short* __restrict__ Bt,
                                              int K,
                                              unsigned short* __restrict__ q_out,
                                              unsigned short* __restrict__ k_out,
                                              unsigned short* __restrict__ vt_out,
                                              float* __restrict__ f_out,
                                              const float* __restrict__ bias) {
  __shared__ short a_lds[2][128 * 32];
  __shared__ short b_lds[2][128 * 32];
  const int tid = threadIdx.x;
  const int wave = tid >> 6, lane = tid & 63;
  const int wm = wave >> 1, wn = wave & 1;
  const int lr = lane & 15, lc = lane >> 4;

  const int id = blockIdx.x;
  const int xcd = id & 7, idc = id >> 3;
  const int bx = xcd * 8 + (idc & 7);
  const int by = idc >> 3;
  const int m0 = bx * 128, n0 = by * 128;

  f32x4 acc[4][4];
  for (int mi = 0; mi < 4; ++mi)
    for (int ni = 0; ni < 4; ++ni) acc[mi][ni] = (f32x4){0.f, 0.f, 0.f, 0.f};

  const unsigned short *ap[2], *bp[2];
  int lb[2];
#pragma unroll
  for (int p = 0; p < 2; ++p) {
    int chunk = p * 256 + wave * 64 + lane;
    int r = chunk >> 2, cc = chunk & 3;
    int c = cc ^ ((r >> 1) & 3);
    ap[p] = A + (size_t)(m0 + r) * K + c * 8;
    bp[p] = Bt + (size_t)(n0 + r) * K + c * 8;
    lb[p] = (p * 256 + wave * 64) * 8;
  }

  const int nks = K >> 5;
#pragma unroll
  for (int p = 0; p < 2; ++p) {
    gll16(ap[p], &a_lds[0][lb[p]]);
    gll16(bp[p], &b_lds[0][lb[p]]);
    ap[p] += 32; bp[p] += 32;
  }

  for (int ks = 0; ks < nks; ++ks) {
    const int buf = ks & 1;
    __builtin_amdgcn_s_barrier();
    __builtin_amdgcn_sched_barrier(0);
    if (ks + 1 < nks) {
#pragma unroll
      for (int p = 0; p < 2; ++p) {
        gll16(ap[p], &a_lds[buf ^ 1][lb[p]]);
        gll16(bp[p], &b_lds[buf ^ 1][lb[p]]);
        ap[p] += 32; bp[p] += 32;
      }
      asm volatile("s_waitcnt vmcnt(4)" ::: "memory");
    } else {
      asm volatile("s_waitcnt vmcnt(0)" ::: "memory");
    }
    __builtin_amdgcn_sched_barrier(0);
    __builtin_amdgcn_s_barrier();
    __builtin_amdgcn_sched_barrier(0);

    bf16x8 af[4], bfrag[4];
#pragma unroll
    for (int mi = 0; mi < 4; ++mi) {
      int r = wm * 64 + mi * 16 + lr;
      af[mi] = *(const bf16x8*)&a_lds[buf][r * 32 + (lc ^ ((r >> 1) & 3)) * 8];
    }
#pragma unroll
    for (int ni = 0; ni < 4; ++ni) {
      int r = wn * 64 + ni * 16 + lr;
      bfrag[ni] = *(const bf16x8*)&b_lds[buf][r * 32 + (lc ^ ((r >> 1) & 3)) * 8];
    }
    __builtin_amdgcn_s_setprio(1);
#pragma unroll
    for (int mi = 0; mi < 4; ++mi)
#pragma unroll
      for (int ni = 0; ni < 4; ++ni)
        acc[mi][ni] = __builtin_amdgcn_mfma_f32_16x16x32_bf16(af[mi], bfrag[ni], acc[mi][ni], 0, 0, 0);
    __builtin_amdgcn_s_setprio(0);
  }

  if (MODE == 0) {
    const int nn0 = n0 + wn * 64 + lr;
    const int which = n0 / 768;
#pragma unroll
    for (int mi = 0; mi < 4; ++mi)
#pragma unroll
      for (int ni = 0; ni < 4; ++ni) {
        int nn = nn0 + ni * 16;
        int rem = nn - which * 768;
        int h = rem >> 6, d = rem & 63;
        int t0v = m0 + wm * 64 + mi * 16 + lc * 4;
        int b = t0v >> 12, t = t0v & (T_ - 1);
        size_t bh = (size_t)(b * H_ + h);
        if (which == 2) {
          unsigned u0, u1;
          asm("v_cvt_pk_bf16_f32 %0, %1, %2" : "=v"(u0) : "v"(acc[mi][ni][0]), "v"(acc[mi][ni][1]));
          asm("v_cvt_pk_bf16_f32 %0, %1, %2" : "=v"(u1) : "v"(acc[mi][ni][2]), "v"(acc[mi][ni][3]));
          uint2 u = {u0, u1};
          *(uint2*)&vt_out[(bh * D_ + d) * T_ + t] = u;
        } else {
#pragma unroll
          for (int r = 0; r < 4; ++r) {
            float av = acc[mi][ni][r];
            if (which == 0) av *= QSCALE;
            unsigned short val = f2bf(av);
            if (which == 0) q_out[(bh * T_ + t + r) * D_ + d] = val;
            else            k_out[(bh * T_ + t + r) * D_ + d] = val;
          }
        }
      }
  } else {
#pragma unroll
    for (int mi = 0; mi < 4; ++mi)
#pragma unroll
      for (int ni = 0; ni < 4; ++ni) {
        int nn = n0 + wn * 64 + ni * 16 + lr;
        float bv = bias[nn];
#pragma unroll
        for (int r = 0; r < 4; ++r) {
          int m = m0 + wm * 64 + mi * 16 + lc * 4 + r;
          f_out[(size_t)m * C_ + nn] = acc[mi][ni][r] + bv;
        }
      }
  }
}

// ---------------- flash attention v11: KVBLK=128, SEQUENTIAL sub-tiles ----------------
// Barriers/stage-sync per 128 keys (half of R8), but compute = two sequential
// 64-key passes (s2/s3 never live with s0/s1 -> VGPR stays ~R8 level, unlike R10).
// Per-XCD dynamic queues (64 workers vs 96 tasks, LPT). 512 blocks, 4 waves.
// Frag-linear LDS (conflict-free); double-buffered 32KB tiles; vmcnt(8).

#define PACK8(SV, PW, O)                                                          \
  do {                                                                            \
    unsigned w0, w1, w2, w3, w4, w5, w6, w7;                                      \
    asm("v_cvt_pk_bf16_f32 %0, %1, %2" : "=v"(w0) : "v"(SV[0]), "v"(SV[1]));      \
    asm("v_cvt_pk_bf16_f32 %0, %1, %2" : "=v"(w1) : "v"(SV[2]), "v"(SV[3]));      \
    asm("v_cvt_pk_bf16_f32 %0, %1, %2" : "=v"(w2) : "v"(SV[4]), "v"(SV[5]));      \
    asm("v_cvt_pk_bf16_f32 %0, %1, %2" : "=v"(w3) : "v"(SV[6]), "v"(SV[7]));      \
    asm("v_cvt_pk_bf16_f32 %0, %1, %2" : "=v"(w4) : "v"(SV[8]), "v"(SV[9]));      \
    asm("v_cvt_pk_bf16_f32 %0, %1, %2" : "=v"(w5) : "v"(SV[10]), "v"(SV[11]));    \
    asm("v_cvt_pk_bf16_f32 %0, %1, %2" : "=v"(w6) : "v"(SV[12]), "v"(SV[13]));    \
    asm("v_cvt_pk_bf16_f32 %0, %1, %2" : "=v"(w7) : "v"(SV[14]), "v"(SV[15]));    \
    asm("v_permlane32_swap_b32 %0, %1" : "+v"(w0), "+v"(w2));                     \
    asm("v_permlane32_swap_b32 %0, %1" : "+v"(w1), "+v"(w3));                     \
    asm("v_permlane32_swap_b32 %0, %1" : "+v"(w4), "+v"(w6));                     \
    asm("v_permlane32_swap_b32 %0, %1" : "+v"(w5), "+v"(w7));                     \
    PW[(O) + 0] = w0; PW[(O) + 1] = w1; PW[(O) + 2] = w2; PW[(O) + 3] = w3;       \
    PW[(O) + 4] = w4; PW[(O) + 5] = w5; PW[(O) + 6] = w6; PW[(O) + 7] = w7;       \
  } while (0)

__global__ __launch_bounds__(256) void flash11_k(const unsigned short* __restrict__ Qg,
                                                 const unsigned short* __restrict__ Kg,
                                                 const unsigned short* __restrict__ Vtg,
                                                 unsigned short* __restrict__ Og,
                                                 unsigned* __restrict__ cnt) {
  __shared__ short k_lds[2][16 * 512];   // 32 KB
  __shared__ short vt_lds[2][16 * 512];  // 32 KB
  __shared__ int task_s;

  const int tid = threadIdx.x;
  const int wave = tid >> 6, lane = tid & 63;
  const int lq = lane & 31, hi = lane >> 5;
  const int xq = blockIdx.x & 7;
  unsigned* myq = cnt + xq * 16;

  for (;;) {
    if (tid == 0) task_s = (int)atomicAdd(myq, 1u);
    __syncthreads();
    const int task = task_s;
    if (task >= QTASK) return;

    const int qi = 31 - task / 3;       // LPT: heavy first
    const int bh = xq * 3 + (task - (task / 3) * 3);
    const int qw = qi * 128 + wave * 32;
    const int q_g = qw + lq;

    const size_t kbase = (size_t)bh * T_ * D_;
    const size_t vbase = (size_t)bh * D_ * T_;

    const unsigned short* qrow = Qg + kbase + (size_t)q_g * D_;
    bf16x8 qf[4];
#pragma unroll
    for (int t = 0; t < 4; ++t) qf[t] = *(const bf16x8*)(qrow + t * 16 + hi * 8);

    f32x16 accT0, accT1;
#pragma unroll
    for (int r = 0; r < 16; ++r) { accT0[r] = 0.f; accT1[r] = 0.f; }
    float lvec[8];
#pragma unroll
    for (int r = 0; r < 8; ++r) lvec[r] = 0.f;
    float m = 0.f;

    const int nt = qi + 1;              // 128-key iterations

    // staging: frag f = wave + p*4 (p=0..3 covers f=0..15)
    const unsigned short *kb_p[4], *vb_p[4];
    int lf[4];
#pragma unroll
    for (int p = 0; p < 4; ++p) {
      int f = wave + p * 4;
      int sub = f >> 3, tt = (f >> 1) & 3, h = f & 1;
      kb_p[p] = Kg + kbase + (size_t)(sub * 64 + h * 32 + lq) * D_ + tt * 16 + hi * 8;
      vb_p[p] = Vtg + vbase + (size_t)(h * 32 + lq) * T_ + sub * 64 + tt * 16 + hi * 8;
      lf[p] = f * 512;
    }

    auto stage = [&](int it, int sb) {
#pragma unroll
      for (int p = 0; p < 4; ++p) {
        gll16(kb_p[p] + (size_t)it * 128 * D_, &k_lds[sb][lf[p]]);
        gll16(vb_p[p] + it * 128, &vt_lds[sb][lf[p]]);
      }
    };

    stage(0, 0);

    for (int j = 0; j < nt; ++j) {
      const int kv = j * 128;
      const int buf = j & 1;

      __builtin_amdgcn_s_barrier();     // all waves done compute(j-1)
      __builtin_amdgcn_sched_barrier(0);
      if (j + 1 < nt) {
        stage(j + 1, buf ^ 1);
        asm volatile("s_waitcnt vmcnt(8)" ::: "memory");  // stage(j) landed
      } else {
        asm volatile("s_waitcnt vmcnt(0)" ::: "memory");
      }
      __builtin_amdgcn_sched_barrier(0);
      __builtin_amdgcn_s_barrier();     // buf[j&1] ready for everyone
      __builtin_amdgcn_sched_barrier(0);

      // ================= sub-tile 0: keys kv .. kv+63 (always active) =================
      {
        const float negm = -m;
        f32x16 s0, s1;
#pragma unroll
        for (int r = 0; r < 16; ++r) { s0[r] = negm; s1[r] = negm; }
        __builtin_amdgcn_s_setprio(1);
#pragma unroll
        for (int t = 0; t < 4; ++t) {
          bf16x8 kf0 = *(const bf16x8*)&k_lds[buf][(t * 2 + 0) * 512 + lane * 8];
          bf16x8 kf1 = *(const bf16x8*)&k_lds[buf][(t * 2 + 1) * 512 + lane * 8];
          s0 = __builtin_amdgcn_mfma_f32_32x32x16_bf16(kf0, qf[t], s0, 0, 0, 0);
          s1 = __builtin_amdgcn_mfma_f32_32x32x16_bf16(kf1, qf[t], s1, 0, 0, 0);
        }
        __builtin_amdgcn_s_setprio(0);

        if (kv + 63 > qw) {
#pragma unroll
          for (int r = 0; r < 16; ++r) {
            int key0 = kv + ((r & 3) + 8 * (r >> 2) + 4 * hi);
            if (key0 > q_g) s0[r] = -INFINITY;
            if (key0 + 32 > q_g) s1[r] = -INFINITY;
          }
        }

        float mx[16];
#pragma unroll
        for (int r = 0; r < 16; ++r) mx[r] = fmaxf(s0[r], s1[r]);
        float a0 = fmaxf(fmaxf(mx[0], mx[1]), mx[2]);
        float a1 = fmaxf(fmaxf(mx[3], mx[4]), mx[5]);
        float a2 = fmaxf(fmaxf(mx[6], mx[7]), mx[8]);
        float a3 = fmaxf(fmaxf(mx[9], mx[10]), mx[11]);
        float a4 = fmaxf(fmaxf(mx[12], mx[13]), mx[14]);
        float rx = fmaxf(fmaxf(fmaxf(a0, a1), fmaxf(a2, a3)), fmaxf(a4, mx[15]));
        rx = fmaxf(rx, __shfl_xor(rx, 32));

        if (!__all(rx <= 8.f)) {
          float dlt = fmaxf(rx, 0.f);
          float al = exp2_hw(-dlt);
          m += dlt;
#pragma unroll
          for (int r = 0; r < 16; ++r) { accT0[r] *= al; accT1[r] *= al; }
#pragma unroll
          for (int r = 0; r < 8; ++r) lvec[r] *= al;
#pragma unroll
          for (int r = 0; r < 16; ++r) { s0[r] -= dlt; s1[r] -= dlt; }
        }
#pragma unroll
        for (int r = 0; r < 16; ++r) s0[r] = exp2_hw(s0[r]);
#pragma unroll
        for (int r = 0; r < 16; ++r) s1[r] = exp2_hw(s1[r]);
#pragma unroll
        for (int r = 0; r < 8; ++r) lvec[r] += (s0[r] + s1[r]) + (s0[r + 8] + s1[r + 8]);

        union { unsigned u[16]; bf16x8 v[4]; } pwu;
        PACK8(s0, pwu.u, 0);
        PACK8(s1, pwu.u, 8);

        __builtin_amdgcn_s_setprio(1);
#pragma unroll
        for (int ks = 0; ks < 4; ++ks) {
          bf16x8 vf0 = *(const bf16x8*)&vt_lds[buf][(ks * 2 + 0) * 512 + lane * 8];
          bf16x8 vf1 = *(const bf16x8*)&vt_lds[buf][(ks * 2 + 1) * 512 + lane * 8];
          accT0 = __builtin_amdgcn_mfma_f32_32x32x16_bf16(vf0, pwu.v[ks], accT0, 0, 0, 0);
          accT1 = __builtin_amdgcn_mfma_f32_32x32x16_bf16(vf1, pwu.v[ks], accT1, 0, 0, 0);
        }
        __builtin_amdgcn_s_setprio(0);
      }

      // ================= sub-tile 1: keys kv+64 .. kv+127 (wave-uniform skip) =========
      if (kv + 64 <= qw + 31) {
        const float negm = -m;
        f32x16 s0, s1;
#pragma unroll
        for (int r = 0; r < 16; ++r) { s0[r] = negm; s1[r] = negm; }
        __builtin_amdgcn_s_setprio(1);
#pragma unroll
        for (int t = 0; t < 4; ++t) {
          bf16x8 kf0 = *(const bf16x8*)&k_lds[buf][(8 + t * 2 + 0) * 512 + lane * 8];
          bf16x8 kf1 = *(const bf16x8*)&k_lds[buf][(8 + t * 2 + 1) * 512 + lane * 8];
          s0 = __builtin_amdgcn_mfma_f32_32x32x16_bf16(kf0, qf[t], s0, 0, 0, 0);
          s1 = __builtin_amdgcn_mfma_f32_32x32x16_bf16(kf1, qf[t], s1, 0, 0, 0);
        }
        __builtin_amdgcn_s_setprio(0);

        if (kv + 127 > qw) {
#pragma unroll
          for (int r = 0; r < 16; ++r) {
            int key0 = kv + 64 + ((r & 3) + 8 * (r >> 2) + 4 * hi);
            if (key0 > q_g) s0[r] = -INFINITY;
            if (key0 + 32 > q_g) s1[r] = -INFINITY;
          }
        }

        float mx[16];
#pragma unroll
        for (int r = 0; r < 16; ++r) mx[r] = fmaxf(s0[r], s1[r]);
        float a0 = fmaxf(fmaxf(mx[0], mx[1]), mx[2]);
        float a1 = fmaxf(fmaxf(mx[3], mx[4]), mx[5]);
        float a2 = fmaxf(fmaxf(mx[6], mx[7]), mx[8]);
        float a3 = fmaxf(fmaxf(mx[9], mx[10]), mx[11]);
        float a4 = fmaxf(fmaxf(mx[12], mx[13]), mx[14]);
        float rx = fmaxf(fmaxf(fmaxf(a0, a1), fmaxf(a2, a3)), fmaxf(a4, mx[15]));
        rx = fmaxf(rx, __shfl_xor(rx, 32));

        if (!__all(rx <= 8.f)) {
          float dlt = fmaxf(rx, 0.f);
          float al = exp2_hw(-dlt);
          m += dlt;
#pragma unroll
          for (int r = 0; r < 16; ++r) { accT0[r] *= al; accT1[r] *= al; }
#pragma unroll
          for (int r = 0; r < 8; ++r) lvec[r] *= al;
#pragma unroll
          for (int r = 0; r < 16; ++r) { s0[r] -= dlt; s1[r] -= dlt; }
        }
#pragma unroll
        for (int r = 0; r < 16; ++r) s0[r] = exp2_hw(s0[r]);
#pragma unroll
        for (int r = 0; r < 16; ++r) s1[r] = exp2_hw(s1[r]);
#pragma unroll
        for (int r = 0; r < 8; ++r) lvec[r] += (s0[r] + s1[r]) + (s0[r + 8] + s1[r + 8]);

        union { unsigned u[16]; bf16x8 v[4]; } pwu;
        PACK8(s0, pwu.u, 0);
        PACK8(s1, pwu.u, 8);

        __builtin_amdgcn_s_setprio(1);
#pragma unroll
        for (int ks = 0; ks < 4; ++ks) {
          bf16x8 vf0 = *(const bf16x8*)&vt_lds[buf][(8 + ks * 2 + 0) * 512 + lane * 8];
          bf16x8 vf1 = *(const bf16x8*)&vt_lds[buf][(8 + ks * 2 + 1) * 512 + lane * 8];
          accT0 = __builtin_amdgcn_mfma_f32_32x32x16_bf16(vf0, pwu.v[ks], accT0, 0, 0, 0);
          accT1 = __builtin_amdgcn_mfma_f32_32x32x16_bf16(vf1, pwu.v[ks], accT1, 0, 0, 0);
        }
        __builtin_amdgcn_s_setprio(0);
      }
    }

    // ---- final l reduce + epilogue ----
    float l = 0.f;
#pragma unroll
    for (int r = 0; r < 8; ++r) l += lvec[r];
    l += __shfl_xor(l, 32);
    const float inv = 1.0f / l;
    const int b = bh / H_, h = bh - b * H_;
    unsigned short* orow = Og + ((size_t)b * T_ + q_g) * C_ + h * D_;
#pragma unroll
    for (int g = 0; g < 4; ++g) {
      int d0 = 8 * g + 4 * hi;
      float e0 = accT0[4 * g + 0] * inv, e1 = accT0[4 * g + 1] * inv;
      float e2 = accT0[4 * g + 2] * inv, e3 = accT0[4 * g + 3] * inv;
      float f0 = accT1[4 * g + 0] * inv, f1 = accT1[4 * g + 1] * inv;
      float f2 = accT1[4 * g + 2] * inv, f3 = accT1[4 * g + 3] * inv;
      uint2 ua, ub;
      asm("v_cvt_pk_bf16_f32 %0, %1, %2" : "=v"(ua.x) : "v"(e0), "v"(e1));
      asm("v_cvt_pk_bf16_f32 %0, %1, %2" : "=v"(ua.y) : "v"(e2), "v"(e3));
      asm("v_cvt_pk_bf16_f32 %0, %1, %2" : "=v"(ub.x) : "v"(f0), "v"(f1));
      asm("v_cvt_pk_bf16_f32 %0, %1, %2" : "=v"(ub.y) : "v"(f2), "v"(f3));
      *(uint2*)(orow + d0) = ua;
      *(uint2*)(orow + 32 + d0) = ub;
    }
    __syncthreads();  // quiesce LDS before next pop
  }
}

// ---------------- launcher ----------------

extern "C" void kernel_launch(void* const* d_in, const int* in_sizes, int n_in,
                              void* d_out, int out_size, void* d_ws, size_t ws_size,
                              hipStream_t stream) {
  const float* x     = (const float*)d_in[0];
  const float* Wqkv  = (const float*)d_in[1];
  const float* Wproj = (const float*)d_in[2];
  const float* bproj = (const float*)d_in[3];
  float* out = (float*)d_out;

  char* ws = (char*)d_ws;
  unsigned short* xbf   = (unsigned short*)(ws);
  unsigned short* wqkvt = (unsigned short*)(ws + 12582912);
  unsigned short* wprjt = (unsigned short*)(ws + 16121856);
  unsigned short* Qb    = (unsigned short*)(ws + 17301504);
  unsigned short* Kb    = (unsigned short*)(ws + 29884416);
  unsigned short* Vtb   = (unsigned short*)(ws + 42467328);
  unsigned*       cnt   = (unsigned*)(ws + 55050240);  // 128 u32

  cast_bf16_k<<<6144, 256, 0, stream>>>(x, xbf, (B_ * T_ * C_) / 4, cnt);
  tpose_cast_k<<<dim3((3 * C_) / 64, C_ / 64), 256, 0, stream>>>(Wqkv, wqkvt, C_, 3 * C_);
  tpose_cast_k<<<dim3(C_ / 64, C_ / 64), 256, 0, stream>>>(Wproj, wprjt, C_, C_);

  gemm_k<0><<<(B_ * T_ / 128) * (3 * C_ / 128), 256, 0, stream>>>(
      xbf, wqkvt, C_, Qb, Kb, Vtb, nullptr, nullptr);

  flash11_k<<<512, 256, 0, stream>>>(Qb, Kb, Vtb, xbf, cnt);

  gemm_k<1><<<(B_ * T_ / 128) * (C_ / 128), 256, 0, stream>>>(
      xbf, wprjt, C_, nullptr, nullptr, nullptr, out, bproj);
}